// Round 1
// baseline (129.818 us; speedup 1.0000x reference)
//
#include <hip/hip_runtime.h>
#include <hip/hip_bf16.h>
#include <math.h>

#define B_ 4
#define S_ 1024
#define H_ 8
#define D_ 64
#define NC 4
#define KD 256           // NC * D_
#define XPITCH 1032      // padded LDS pitch (shorts)

typedef __attribute__((ext_vector_type(8))) short short8;
typedef __attribute__((ext_vector_type(4))) float f32x4;

__device__ __forceinline__ short f2b(float v) {
  unsigned int u = __builtin_bit_cast(unsigned int, v);
  unsigned int r = (u + 0x7fffu + ((u >> 16) & 1u)) >> 16;
  return (short)(unsigned short)r;
}

// ------------------------------------------------------------------
// Kernel 1: monarch transform.  One block per (bh, src, d-chunk16).
// Writes Qhat/Khat as bf16 [bh][s=1024][kdim=256], kdim = i*64 + d.
// Softmax(weights) folded into Qhat.
// ------------------------------------------------------------------
__global__ __launch_bounds__(256) void monarch_transform(
    const float* __restrict__ Q, const float* __restrict__ Kv,
    const float* __restrict__ M1L, const float* __restrict__ M1R,
    const float* __restrict__ M2L, const float* __restrict__ M2R,
    const float* __restrict__ W, const int* __restrict__ periods,
    short* __restrict__ Qh, short* __restrict__ Kh)
{
  const int blk = blockIdx.x;
  const int dc  = blk & 3;          // d-chunk (16 d's)
  const int src = (blk >> 2) & 1;   // 0 = queries, 1 = keys
  const int bh  = blk >> 3;         // 0..31
  const int b   = bh >> 3;
  const int h   = bh & 7;

  const float* X  = src ? Kv  : Q;
  const float* Lm = src ? M2L : M1L;
  const float* Rm = src ? M2R : M1R;
  short* Out      = src ? Kh  : Qh;

  __shared__ short xb[16 * XPITCH];

  const int tid  = threadIdx.x;
  const int lane = tid & 63;
  const int w    = tid >> 6;
  const int l15  = lane & 15;
  const int l4   = lane >> 4;

  // softmax weights (q side only)
  float ws[4];
  {
    float w0 = W[b*4+0], w1 = W[b*4+1], w2 = W[b*4+2], w3 = W[b*4+3];
    float mx = fmaxf(fmaxf(w0, w1), fmaxf(w2, w3));
    float e0 = expf(w0-mx), e1 = expf(w1-mx), e2 = expf(w2-mx), e3 = expf(w3-mx);
    float inv = 1.0f / (e0+e1+e2+e3);
    ws[0]=e0*inv; ws[1]=e1*inv; ws[2]=e2*inv; ws[3]=e3*inv;
  }

  const int d_a = tid & 15;  // phase-A d
  const int jg  = tid >> 4;  // phase-A j-group

  for (int i = 0; i < NC; ++i) {
    const int p  = periods[i];         // power of two in {1,2,4,8}
    const int lp = 31 - __clz(p);
    const int fm1 = (1024 >> lp) - 1;  // f-1
    const float scale = src ? 1.0f : ws[i];

    __syncthreads();  // protect xb from previous iteration's phase E

    // ---- Phase A: t2[j] = x[perm_in(j)], staged as bf16 ----
    {
      const float* xbase = X + (size_t)b*524288 + h*64 + dc*16 + d_a;
      for (int jj = 0; jj < 64; ++jj) {
        int j = jg*64 + jj;
        int m = ((j & 31) << 5) | (j >> 5);                 // swap32
        int s = ((m & (p-1)) << (10 - lp)) + (m >> lp);     // swap_p
        xb[d_a * XPITCH + j] = f2b(xbase[(size_t)s * 512]);
      }
    }
    __syncthreads();

    // ---- Stage 1: t3 = blockdiag(L) * t2 ----
    f32x4 acc[8][2];
    #pragma unroll
    for (int bi = 0; bi < 8; ++bi)
      #pragma unroll
      for (int rt = 0; rt < 2; ++rt) acc[bi][rt] = (f32x4){0.f,0.f,0.f,0.f};

    #pragma unroll
    for (int bi = 0; bi < 8; ++bi) {
      int bb = w*8 + bi;
      short8 a = *(const short8*)&xb[l15 * XPITCH + bb*32 + l4*8];
      #pragma unroll
      for (int rt = 0; rt < 2; ++rt) {
        const float* lrow = Lm + (((size_t)(i*32 + bb)*32 + rt*16 + l15) * 32) + l4*8;
        short8 bf;
        #pragma unroll
        for (int e = 0; e < 8; ++e) bf[e] = f2b(lrow[e]);
        acc[bi][rt] = __builtin_amdgcn_mfma_f32_16x16x32_bf16(a, bf, acc[bi][rt], 0, 0, 0);
      }
    }
    __syncthreads();

    // write t4 = swap32(t3) back into xb
    #pragma unroll
    for (int bi = 0; bi < 8; ++bi) {
      int bb = w*8 + bi;
      #pragma unroll
      for (int rt = 0; rt < 2; ++rt)
        #pragma unroll
        for (int rr = 0; rr < 4; ++rr) {
          int d = l4*4 + rr;
          int r = rt*16 + l15;
          xb[d * XPITCH + r*32 + bb] = f2b(acc[bi][rt][rr]);
        }
    }
    __syncthreads();

    // ---- Stage 2: t5 = blockdiag(R) * t4 ----
    #pragma unroll
    for (int bi = 0; bi < 8; ++bi)
      #pragma unroll
      for (int rt = 0; rt < 2; ++rt) acc[bi][rt] = (f32x4){0.f,0.f,0.f,0.f};

    #pragma unroll
    for (int bi = 0; bi < 8; ++bi) {
      int bb = w*8 + bi;
      short8 a = *(const short8*)&xb[l15 * XPITCH + bb*32 + l4*8];
      #pragma unroll
      for (int rt = 0; rt < 2; ++rt) {
        const float* rrow = Rm + (((size_t)(i*32 + bb)*32 + rt*16 + l15) * 32) + l4*8;
        short8 bf;
        #pragma unroll
        for (int e = 0; e < 8; ++e) bf[e] = f2b(rrow[e]);
        acc[bi][rt] = __builtin_amdgcn_mfma_f32_16x16x32_bf16(a, bf, acc[bi][rt], 0, 0, 0);
      }
    }
    __syncthreads();

    // write t5 at final permuted position jo = swap_f(swap32(j)), scaled
    #pragma unroll
    for (int bi = 0; bi < 8; ++bi) {
      int bb = w*8 + bi;
      #pragma unroll
      for (int rt = 0; rt < 2; ++rt)
        #pragma unroll
        for (int rr = 0; rr < 4; ++rr) {
          int d = l4*4 + rr;
          int r = rt*16 + l15;
          int m = r*32 + bb;                         // swap32(j)
          int jo = ((m & fm1) << lp) + (m >> (10 - lp));
          xb[d * XPITCH + jo] = f2b(acc[bi][rt][rr] * scale);
        }
    }
    __syncthreads();

    // ---- Phase E: coalesced-ish write to [s][kdim] layout ----
    {
      size_t obase = ((size_t)bh * 1024) * 256 + i*64 + dc*16;
      for (int r4 = 0; r4 < 4; ++r4) {
        int jo = tid*4 + r4;
        short8 v0, v1;
        #pragma unroll
        for (int e = 0; e < 8; ++e) v0[e] = xb[e * XPITCH + jo];
        #pragma unroll
        for (int e = 0; e < 8; ++e) v1[e] = xb[(8+e) * XPITCH + jo];
        short* op = Out + obase + (size_t)jo * 256;
        *(short8*)(op)     = v0;
        *(short8*)(op + 8) = v1;
      }
    }
  }
}

// ------------------------------------------------------------------
// Kernel 2: batched GEMM  out[bh] = Qhat[bh]^T-style product:
// out[s,l] = sum_k Qhat[s,k]*Khat[l,k], K=256, 128x128 tiles,
// global_load_lds staging with XOR-swizzled LDS (swizzle on source+read).
// ------------------------------------------------------------------
__global__ __launch_bounds__(256) void score_gemm(
    const short* __restrict__ Qh, const short* __restrict__ Kh,
    float* __restrict__ Out)
{
  const int bh = blockIdx.y;
  const int tm = (blockIdx.x >> 3) << 7;
  const int tn = (blockIdx.x & 7) << 7;

  __shared__ short As[128*64];
  __shared__ short Bs[128*64];

  const int tid  = threadIdx.x;
  const int lane = tid & 63;
  const int w    = tid >> 6;
  const int wm   = (w >> 1) << 6;
  const int wn   = (w & 1) << 6;
  const int l15  = lane & 15;
  const int l4   = lane >> 4;

  const short* Qb = Qh + (size_t)bh * (1024*256);
  const short* Kb = Kh + (size_t)bh * (1024*256);

  const int lrow = lane >> 3;                    // row within 8-row segment
  const int kch  = (((lane & 7) ^ lrow) << 3);   // inverse-swizzled source k-offset

  f32x4 acc[4][4];
  #pragma unroll
  for (int fm = 0; fm < 4; ++fm)
    #pragma unroll
    for (int fn = 0; fn < 4; ++fn) acc[fm][fn] = (f32x4){0.f,0.f,0.f,0.f};

  for (int kt = 0; kt < 4; ++kt) {
    #pragma unroll
    for (int q0 = 0; q0 < 4; ++q0) {
      int seg = w*4 + q0;
      int row = seg*8 + lrow;
      const short* srcA = Qb + (size_t)(tm + row)*256 + kt*64 + kch;
      const short* srcB = Kb + (size_t)(tn + row)*256 + kt*64 + kch;
      __builtin_amdgcn_global_load_lds(
          (const __attribute__((address_space(1))) unsigned int*)srcA,
          (__attribute__((address_space(3))) unsigned int*)&As[seg*512], 16, 0, 0);
      __builtin_amdgcn_global_load_lds(
          (const __attribute__((address_space(1))) unsigned int*)srcB,
          (__attribute__((address_space(3))) unsigned int*)&Bs[seg*512], 16, 0, 0);
    }
    __syncthreads();

    #pragma unroll
    for (int kk = 0; kk < 2; ++kk) {
      short8 af[4], bf[4];
      #pragma unroll
      for (int fm = 0; fm < 4; ++fm) {
        int row = wm + fm*16 + l15;
        int kl  = kk*32 + l4*8;
        af[fm] = *(const short8*)&As[row*64 + (kl ^ ((row & 7) << 3))];
      }
      #pragma unroll
      for (int fn = 0; fn < 4; ++fn) {
        int row = wn + fn*16 + l15;
        int kl  = kk*32 + l4*8;
        bf[fn] = *(const short8*)&Bs[row*64 + (kl ^ ((row & 7) << 3))];
      }
      #pragma unroll
      for (int fm = 0; fm < 4; ++fm)
        #pragma unroll
        for (int fn = 0; fn < 4; ++fn)
          acc[fm][fn] = __builtin_amdgcn_mfma_f32_16x16x32_bf16(af[fm], bf[fn], acc[fm][fn], 0, 0, 0);
    }
    __syncthreads();
  }

  float* Ob = Out + ((size_t)bh << 20);
  #pragma unroll
  for (int fm = 0; fm < 4; ++fm)
    #pragma unroll
    for (int fn = 0; fn < 4; ++fn)
      #pragma unroll
      for (int rr = 0; rr < 4; ++rr) {
        int row = tm + wm + fm*16 + l4*4 + rr;
        int col = tn + wn + fn*16 + l15;
        Ob[((size_t)row << 10) + col] = acc[fm][fn][rr];
      }
}

extern "C" void kernel_launch(void* const* d_in, const int* in_sizes, int n_in,
                              void* d_out, int out_size, void* d_ws, size_t ws_size,
                              hipStream_t stream) {
  const float* Q   = (const float*)d_in[0];
  const float* Kv  = (const float*)d_in[1];
  const float* M1L = (const float*)d_in[2];
  const float* M1R = (const float*)d_in[3];
  const float* M2L = (const float*)d_in[4];
  const float* M2R = (const float*)d_in[5];
  const float* W   = (const float*)d_in[6];
  const int* per   = (const int*)d_in[7];
  float* Out       = (float*)d_out;

  short* Qhat = (short*)d_ws;                          // 32*1024*256 bf16 = 16.8 MB
  short* Khat = Qhat + (size_t)32 * 1024 * 256;        // same

  monarch_transform<<<dim3(256), dim3(256), 0, stream>>>(
      Q, Kv, M1L, M1R, M2L, M2R, W, per, Qhat, Khat);

  score_gemm<<<dim3(64, 32), dim3(256), 0, stream>>>(Qhat, Khat, Out);
}

// Round 2
// 87.636 us; speedup vs baseline: 1.4813x; 1.4813x over previous
//
#include <hip/hip_runtime.h>
#include <hip/hip_bf16.h>
#include <math.h>

typedef __attribute__((ext_vector_type(8))) short short8;
typedef __attribute__((ext_vector_type(4))) short short4v;
typedef __attribute__((ext_vector_type(4))) float f32x4;
typedef __attribute__((ext_vector_type(4))) int int4v;

#define XP 1032

__device__ __forceinline__ short f2b(float v) {
  unsigned int u = __builtin_bit_cast(unsigned int, v);
  unsigned int r = (u + 0x7fffu + ((u >> 16) & 1u)) >> 16;
  return (short)(unsigned short)r;
}
__device__ __forceinline__ int rol10(int x, int k) {
  return ((x << k) | (x >> (10 - k))) & 1023;
}
__device__ __forceinline__ int ror10(int x, int k) {
  return ((x >> k) | (x << (10 - k))) & 1023;
}
__device__ __forceinline__ int swzj(int j) {
  return j ^ (((j >> 6) & 7) << 3);
}

// ------------------------------------------------------------------
// Kernel 0: convert the four monarch weight tensors fp32 -> bf16.
// Lbf layout: [slot][131072], slot = {M1L, M1R, M2L, M2R}.
// ------------------------------------------------------------------
__global__ __launch_bounds__(256) void conv_lr(
    const float* __restrict__ M1L, const float* __restrict__ M1R,
    const float* __restrict__ M2L, const float* __restrict__ M2R,
    short* __restrict__ Lbf)
{
  int g = blockIdx.x * 256 + threadIdx.x;   // 0..32767, 4 floats each
  const float* srcs[4] = {M1L, M1R, M2L, M2R};
  #pragma unroll
  for (int t = 0; t < 4; ++t) {
    float4 v = *(const float4*)(srcs[t] + (size_t)g * 4);
    short4v o = { f2b(v.x), f2b(v.y), f2b(v.z), f2b(v.w) };
    *(short4v*)(Lbf + (size_t)t * 131072 + (size_t)g * 4) = o;
  }
}

// ------------------------------------------------------------------
// Kernel 1: monarch transform, one block per (bh, src, dc, i).
// All swaps expressed as 10-bit index rotations.
// Writes Qhat/Khat bf16 [bh][s=1024][kd=256], kd = i*64 + dc*16 + d.
// softmax(weights) folded into Qhat.
// ------------------------------------------------------------------
template<bool USEBF>
__global__ __launch_bounds__(256) void monarch_transform2(
    const float* __restrict__ Q, const float* __restrict__ Kv,
    const float* __restrict__ M1L, const float* __restrict__ M1R,
    const float* __restrict__ M2L, const float* __restrict__ M2R,
    const short* __restrict__ Lbf,
    const float* __restrict__ W, const int* __restrict__ periods,
    short* __restrict__ Qh, short* __restrict__ Kh)
{
  const int blk  = blockIdx.x;
  const int i    = blk >> 8;       // component: partners spaced 256 apart -> same XCD
  const int rest = blk & 255;
  const int dc   = rest & 3;
  const int src  = (rest >> 2) & 1;
  const int bh   = rest >> 3;
  const int b    = bh >> 3;
  const int h    = bh & 7;

  __shared__ short xb[16 * XP];    // 33 KB; reused as xb2[1024][16] at the end

  const int tid  = threadIdx.x;
  const int lane = tid & 63;
  const int w    = tid >> 6;
  const int l15  = lane & 15;
  const int l4   = lane >> 4;

  const int p   = periods[i];           // {1,2,4,8}
  const int lp  = 31 - __clz(p);
  const int kin = 5 + lp;               // input rotation
  const int kf  = 5 - lp;               // output rotation

  float scale = 1.0f;
  if (src == 0) {
    float w0 = W[b*4+0], w1 = W[b*4+1], w2 = W[b*4+2], w3 = W[b*4+3];
    float mx = fmaxf(fmaxf(w0, w1), fmaxf(w2, w3));
    float e0 = expf(w0-mx), e1 = expf(w1-mx), e2 = expf(w2-mx), e3 = expf(w3-mx);
    float inv = 1.0f / (e0+e1+e2+e3);
    float e[4] = {e0, e1, e2, e3};
    scale = e[i] * inv;
  }

  // ---- Phase 1: coalesced load of X, stage into LDS in t2 order ----
  // t2[d][j] = x[d][ror10(j, kin)]  =>  write x[d][s] at j = rol10(s, kin)
  {
    const int dgrp = tid & 3;           // which float4 of the 16-d chunk
    const int srow = tid >> 2;          // 0..63
    const float* xbase = (src ? Kv : Q)
        + (size_t)b*524288 + h*64 + dc*16 + dgrp*4;
    const int jlo = rol10(srow, kin);   // srow bits (0..5) rotated
    #pragma unroll
    for (int it = 0; it < 16; ++it) {
      int s = it*64 + srow;
      float4 v = *(const float4*)(xbase + (size_t)s * 512);
      int j  = rol10(it << 6, kin) | jlo;   // disjoint bit fields
      int ja = swzj(j);
      xb[(dgrp*4+0)*XP + ja] = f2b(v.x);
      xb[(dgrp*4+1)*XP + ja] = f2b(v.y);
      xb[(dgrp*4+2)*XP + ja] = f2b(v.z);
      xb[(dgrp*4+3)*XP + ja] = f2b(v.w);
    }
  }
  __syncthreads();

  const short* LBs = Lbf + (size_t)(src ? 2 : 0) * 131072;  // L slot
  const short* RBs = Lbf + (size_t)(src ? 3 : 1) * 131072;  // R slot
  const float* LF  = src ? M2L : M1L;
  const float* RF  = src ? M2R : M1R;

  f32x4 acc[8][2];

  // ---- Stage 1: t3 = blockdiag(L) * t2 ----
  #pragma unroll
  for (int bi = 0; bi < 8; ++bi)
    #pragma unroll
    for (int rt = 0; rt < 2; ++rt) acc[bi][rt] = (f32x4){0.f,0.f,0.f,0.f};

  #pragma unroll
  for (int bi = 0; bi < 8; ++bi) {
    int bb = w*8 + bi;
    int j0 = bb*32 + l4*8;
    short8 a = *(const short8*)&xb[l15*XP + swzj(j0)];
    #pragma unroll
    for (int rt = 0; rt < 2; ++rt) {
      int roff = ((i*32 + bb)*32 + rt*16 + l15)*32 + l4*8;
      short8 bf;
      if (USEBF) {
        bf = *(const short8*)(LBs + roff);
      } else {
        float4 u0 = *(const float4*)(LF + roff);
        float4 u1 = *(const float4*)(LF + roff + 4);
        bf[0]=f2b(u0.x); bf[1]=f2b(u0.y); bf[2]=f2b(u0.z); bf[3]=f2b(u0.w);
        bf[4]=f2b(u1.x); bf[5]=f2b(u1.y); bf[6]=f2b(u1.z); bf[7]=f2b(u1.w);
      }
      acc[bi][rt] = __builtin_amdgcn_mfma_f32_16x16x32_bf16(a, bf, acc[bi][rt], 0, 0, 0);
    }
  }
  __syncthreads();

  // ---- t4 pack-write: t4[d][r*32+bb] = t3[bb*32+r]; 8 consecutive j per lane ----
  #pragma unroll
  for (int rt = 0; rt < 2; ++rt)
    #pragma unroll
    for (int rr = 0; rr < 4; ++rr) {
      short8 v;
      #pragma unroll
      for (int bi = 0; bi < 8; ++bi) v[bi] = f2b(acc[bi][rt][rr]);
      int r  = rt*16 + l15;
      int d  = l4*4 + rr;
      int j2 = r*32 + w*8;
      *(short8*)&xb[d*XP + swzj(j2)] = v;
    }
  __syncthreads();

  // ---- Stage 2: t5 = blockdiag(R) * t4 ----
  #pragma unroll
  for (int bi = 0; bi < 8; ++bi)
    #pragma unroll
    for (int rt = 0; rt < 2; ++rt) acc[bi][rt] = (f32x4){0.f,0.f,0.f,0.f};

  #pragma unroll
  for (int bi = 0; bi < 8; ++bi) {
    int bb = w*8 + bi;
    int j0 = bb*32 + l4*8;
    short8 a = *(const short8*)&xb[l15*XP + swzj(j0)];
    #pragma unroll
    for (int rt = 0; rt < 2; ++rt) {
      int roff = ((i*32 + bb)*32 + rt*16 + l15)*32 + l4*8;
      short8 bf;
      if (USEBF) {
        bf = *(const short8*)(RBs + roff);
      } else {
        float4 u0 = *(const float4*)(RF + roff);
        float4 u1 = *(const float4*)(RF + roff + 4);
        bf[0]=f2b(u0.x); bf[1]=f2b(u0.y); bf[2]=f2b(u0.z); bf[3]=f2b(u0.w);
        bf[4]=f2b(u1.x); bf[5]=f2b(u1.y); bf[6]=f2b(u1.z); bf[7]=f2b(u1.w);
      }
      acc[bi][rt] = __builtin_amdgcn_mfma_f32_16x16x32_bf16(a, bf, acc[bi][rt], 0, 0, 0);
    }
  }
  __syncthreads();

  // ---- Phase 5: scatter t5 -> xb2[jo][16 d] (b64, swizzled), scaled ----
  // t5 index m = bb2*32 + r2 lands at jo = ror10(m, kf)
  #pragma unroll
  for (int bi = 0; bi < 8; ++bi)
    #pragma unroll
    for (int rt = 0; rt < 2; ++rt) {
      int m  = (w*8 + bi)*32 + rt*16 + l15;
      int jo = ror10(m, kf);
      int sw = (jo >> 5) & 3;
      unsigned int lo = (unsigned short)f2b(acc[bi][rt][0] * scale)
                      | ((unsigned int)(unsigned short)f2b(acc[bi][rt][1] * scale) << 16);
      unsigned int hi = (unsigned short)f2b(acc[bi][rt][2] * scale)
                      | ((unsigned int)(unsigned short)f2b(acc[bi][rt][3] * scale) << 16);
      uint2 pv; pv.x = lo; pv.y = hi;
      *(uint2*)&xb[jo*16 + ((l4 ^ sw) << 2)] = pv;   // d-group l4 stored at (l4^sw)
    }
  __syncthreads();

  // ---- Phase 6: coalesced global write [s][kd] ----
  {
    short* Out = src ? Kh : Qh;
    size_t obase = ((size_t)bh * 1024) * 256 + i*64 + dc*16;
    #pragma unroll
    for (int it2 = 0; it2 < 4; ++it2) {
      int jo = it2*256 + tid;
      int sw = (jo >> 5) & 3;
      uint2 g[4];
      #pragma unroll
      for (int gg = 0; gg < 4; ++gg)
        g[gg] = *(const uint2*)&xb[jo*16 + (((gg ^ sw)) << 2)];
      int4v lo = {(int)g[0].x, (int)g[0].y, (int)g[1].x, (int)g[1].y};
      int4v hi = {(int)g[2].x, (int)g[2].y, (int)g[3].x, (int)g[3].y};
      short* op = Out + obase + (size_t)jo * 256;
      *(int4v*)(op)     = lo;
      *(int4v*)(op + 8) = hi;
    }
  }
}

// ------------------------------------------------------------------
// Kernel 2: batched GEMM  out[s,l] = sum_k Qhat[s,k]*Khat[l,k], K=256,
// 128x128 tiles, global_load_lds staging with XOR-swizzled LDS.
// ------------------------------------------------------------------
__global__ __launch_bounds__(256) void score_gemm(
    const short* __restrict__ Qh, const short* __restrict__ Kh,
    float* __restrict__ Out)
{
  const int bh = blockIdx.y;
  const int tm = (blockIdx.x >> 3) << 7;
  const int tn = (blockIdx.x & 7) << 7;

  __shared__ short As[128*64];
  __shared__ short Bs[128*64];

  const int tid  = threadIdx.x;
  const int lane = tid & 63;
  const int w    = tid >> 6;
  const int wm   = (w >> 1) << 6;
  const int wn   = (w & 1) << 6;
  const int l15  = lane & 15;
  const int l4   = lane >> 4;

  const short* Qb = Qh + (size_t)bh * (1024*256);
  const short* Kb = Kh + (size_t)bh * (1024*256);

  const int lrow = lane >> 3;                    // row within 8-row segment
  const int kch  = (((lane & 7) ^ lrow) << 3);   // inverse-swizzled source k-offset

  f32x4 acc[4][4];
  #pragma unroll
  for (int fm = 0; fm < 4; ++fm)
    #pragma unroll
    for (int fn = 0; fn < 4; ++fn) acc[fm][fn] = (f32x4){0.f,0.f,0.f,0.f};

  for (int kt = 0; kt < 4; ++kt) {
    #pragma unroll
    for (int q0 = 0; q0 < 4; ++q0) {
      int seg = w*4 + q0;
      int row = seg*8 + lrow;
      const short* srcA = Qb + (size_t)(tm + row)*256 + kt*64 + kch;
      const short* srcB = Kb + (size_t)(tn + row)*256 + kt*64 + kch;
      __builtin_amdgcn_global_load_lds(
          (const __attribute__((address_space(1))) unsigned int*)srcA,
          (__attribute__((address_space(3))) unsigned int*)&As[seg*512], 16, 0, 0);
      __builtin_amdgcn_global_load_lds(
          (const __attribute__((address_space(1))) unsigned int*)srcB,
          (__attribute__((address_space(3))) unsigned int*)&Bs[seg*512], 16, 0, 0);
    }
    __syncthreads();

    #pragma unroll
    for (int kk = 0; kk < 2; ++kk) {
      short8 af[4], bf[4];
      #pragma unroll
      for (int fm = 0; fm < 4; ++fm) {
        int row = wm + fm*16 + l15;
        int kl  = kk*32 + l4*8;
        af[fm] = *(const short8*)&As[row*64 + (kl ^ ((row & 7) << 3))];
      }
      #pragma unroll
      for (int fn = 0; fn < 4; ++fn) {
        int row = wn + fn*16 + l15;
        int kl  = kk*32 + l4*8;
        bf[fn] = *(const short8*)&Bs[row*64 + (kl ^ ((row & 7) << 3))];
      }
      #pragma unroll
      for (int fm = 0; fm < 4; ++fm)
        #pragma unroll
        for (int fn = 0; fn < 4; ++fn)
          acc[fm][fn] = __builtin_amdgcn_mfma_f32_16x16x32_bf16(af[fm], bf[fn], acc[fm][fn], 0, 0, 0);
    }
    __syncthreads();
  }

  float* Ob = Out + ((size_t)bh << 20);
  #pragma unroll
  for (int fm = 0; fm < 4; ++fm)
    #pragma unroll
    for (int fn = 0; fn < 4; ++fn)
      #pragma unroll
      for (int rr = 0; rr < 4; ++rr) {
        int row = tm + wm + fm*16 + l4*4 + rr;
        int col = tn + wn + fn*16 + l15;
        Ob[((size_t)row << 10) + col] = acc[fm][fn][rr];
      }
}

extern "C" void kernel_launch(void* const* d_in, const int* in_sizes, int n_in,
                              void* d_out, int out_size, void* d_ws, size_t ws_size,
                              hipStream_t stream) {
  const float* Q   = (const float*)d_in[0];
  const float* Kv  = (const float*)d_in[1];
  const float* M1L = (const float*)d_in[2];
  const float* M1R = (const float*)d_in[3];
  const float* M2L = (const float*)d_in[4];
  const float* M2R = (const float*)d_in[5];
  const float* W   = (const float*)d_in[6];
  const int* per   = (const int*)d_in[7];
  float* Out       = (float*)d_out;

  const size_t qsz = (size_t)32 * 1024 * 256;     // 8388608 shorts each
  short* Qhat = (short*)d_ws;
  short* Khat = Qhat + qsz;
  short* Lbf  = Khat + qsz;
  const size_t need = (qsz * 2 + (size_t)4 * 131072) * sizeof(short);
  const bool usebf = (ws_size >= need);

  if (usebf) {
    conv_lr<<<dim3(128), dim3(256), 0, stream>>>(M1L, M1R, M2L, M2R, Lbf);
    monarch_transform2<true><<<dim3(1024), dim3(256), 0, stream>>>(
        Q, Kv, M1L, M1R, M2L, M2R, Lbf, W, per, Qhat, Khat);
  } else {
    monarch_transform2<false><<<dim3(1024), dim3(256), 0, stream>>>(
        Q, Kv, M1L, M1R, M2L, M2R, Lbf, W, per, Qhat, Khat);
  }

  score_gemm<<<dim3(64, 32), dim3(256), 0, stream>>>(Qhat, Khat, Out);
}

// Round 3
// 79.857 us; speedup vs baseline: 1.6256x; 1.0974x over previous
//
#include <hip/hip_runtime.h>
#include <hip/hip_bf16.h>
#include <math.h>

typedef __attribute__((ext_vector_type(8))) short short8;
typedef __attribute__((ext_vector_type(4))) short short4v;
typedef __attribute__((ext_vector_type(4))) float f32x4;
typedef __attribute__((ext_vector_type(4))) int int4v;

#define XP 1032

__device__ __forceinline__ short f2b(float v) {
  unsigned int u = __builtin_bit_cast(unsigned int, v);
  unsigned int r = (u + 0x7fffu + ((u >> 16) & 1u)) >> 16;
  return (short)(unsigned short)r;
}
__device__ __forceinline__ int rol10(int x, int k) {
  return ((x << k) | (x >> (10 - k))) & 1023;
}
__device__ __forceinline__ int ror10(int x, int k) {
  return ((x >> k) | (x << (10 - k))) & 1023;
}
__device__ __forceinline__ int swzj(int j) {
  return j ^ (((j >> 6) & 7) << 3);
}

// ------------------------------------------------------------------
// Kernel 0: convert the four monarch weight tensors fp32 -> bf16.
// Lbf layout: [slot][131072], slot = {M1L, M1R, M2L, M2R}.
// ------------------------------------------------------------------
__global__ __launch_bounds__(256) void conv_lr(
    const float* __restrict__ M1L, const float* __restrict__ M1R,
    const float* __restrict__ M2L, const float* __restrict__ M2R,
    short* __restrict__ Lbf)
{
  int g = blockIdx.x * 256 + threadIdx.x;   // 0..32767, 4 floats each
  const float* srcs[4] = {M1L, M1R, M2L, M2R};
  #pragma unroll
  for (int t = 0; t < 4; ++t) {
    float4 v = *(const float4*)(srcs[t] + (size_t)g * 4);
    short4v o = { f2b(v.x), f2b(v.y), f2b(v.z), f2b(v.w) };
    *(short4v*)(Lbf + (size_t)t * 131072 + (size_t)g * 4) = o;
  }
}

// ------------------------------------------------------------------
// Kernel 1: monarch transform, one block per (bh, src, dc, i).
// XCD-affine decode: xcd = blk&7 owns bh group xcd*4..xcd*4+3 (same
// grouping as score_gemm, so Qhat/Khat panels stay in that XCD's L2).
// i-partners of an X slice differ only in blk bits 5-6 -> same XCD.
// Writes Qhat/Khat bf16 [bh][s=1024][kd=256], kd = i*64 + dc*16 + d.
// softmax(weights) folded into Qhat.
// ------------------------------------------------------------------
template<bool USEBF>
__global__ __launch_bounds__(256) void monarch_transform2(
    const float* __restrict__ Q, const float* __restrict__ Kv,
    const float* __restrict__ M1L, const float* __restrict__ M1R,
    const float* __restrict__ M2L, const float* __restrict__ M2R,
    const short* __restrict__ Lbf,
    const float* __restrict__ W, const int* __restrict__ periods,
    short* __restrict__ Qh, short* __restrict__ Kh)
{
  const int blk  = blockIdx.x;
  const int xcd  = blk & 7;
  const int seq  = blk >> 3;
  const int bh   = (xcd << 2) | (seq & 3);
  const int i    = (seq >> 2) & 3;
  const int src  = (seq >> 4) & 1;
  const int dc   = (seq >> 5) & 3;
  const int b    = bh >> 3;
  const int h    = bh & 7;

  __shared__ short xb[16 * XP];    // 33 KB; reused as xb2[1024][16] at the end

  const int tid  = threadIdx.x;
  const int lane = tid & 63;
  const int w    = tid >> 6;
  const int l15  = lane & 15;
  const int l4   = lane >> 4;

  const int p   = periods[i];           // {1,2,4,8}
  const int lp  = 31 - __clz(p);
  const int kin = 5 + lp;               // input rotation
  const int kf  = 5 - lp;               // output rotation

  float scale = 1.0f;
  if (src == 0) {
    float w0 = W[b*4+0], w1 = W[b*4+1], w2 = W[b*4+2], w3 = W[b*4+3];
    float mx = fmaxf(fmaxf(w0, w1), fmaxf(w2, w3));
    float e0 = expf(w0-mx), e1 = expf(w1-mx), e2 = expf(w2-mx), e3 = expf(w3-mx);
    float inv = 1.0f / (e0+e1+e2+e3);
    float e[4] = {e0, e1, e2, e3};
    scale = e[i] * inv;
  }

  // ---- Phase 1: coalesced load of X, stage into LDS in t2 order ----
  // t2[d][j] = x[d][ror10(j, kin)]  =>  write x[d][s] at j = rol10(s, kin)
  {
    const int dgrp = tid & 3;           // which float4 of the 16-d chunk
    const int srow = tid >> 2;          // 0..63
    const float* xbase = (src ? Kv : Q)
        + (size_t)b*524288 + h*64 + dc*16 + dgrp*4;
    const int jlo = rol10(srow, kin);   // srow bits (0..5) rotated
    #pragma unroll
    for (int it = 0; it < 16; ++it) {
      int s = it*64 + srow;
      float4 v = *(const float4*)(xbase + (size_t)s * 512);
      int j  = rol10(it << 6, kin) | jlo;   // disjoint bit fields
      int ja = swzj(j);
      xb[(dgrp*4+0)*XP + ja] = f2b(v.x);
      xb[(dgrp*4+1)*XP + ja] = f2b(v.y);
      xb[(dgrp*4+2)*XP + ja] = f2b(v.z);
      xb[(dgrp*4+3)*XP + ja] = f2b(v.w);
    }
  }
  __syncthreads();

  const short* LBs = Lbf + (size_t)(src ? 2 : 0) * 131072;  // L slot
  const short* RBs = Lbf + (size_t)(src ? 3 : 1) * 131072;  // R slot
  const float* LF  = src ? M2L : M1L;
  const float* RF  = src ? M2R : M1R;

  f32x4 acc[8][2];

  // ---- Stage 1: t3 = blockdiag(L) * t2 ----
  #pragma unroll
  for (int bi = 0; bi < 8; ++bi)
    #pragma unroll
    for (int rt = 0; rt < 2; ++rt) acc[bi][rt] = (f32x4){0.f,0.f,0.f,0.f};

  #pragma unroll
  for (int bi = 0; bi < 8; ++bi) {
    int bb = w*8 + bi;
    int j0 = bb*32 + l4*8;
    short8 a = *(const short8*)&xb[l15*XP + swzj(j0)];
    #pragma unroll
    for (int rt = 0; rt < 2; ++rt) {
      int roff = ((i*32 + bb)*32 + rt*16 + l15)*32 + l4*8;
      short8 bf;
      if (USEBF) {
        bf = *(const short8*)(LBs + roff);
      } else {
        float4 u0 = *(const float4*)(LF + roff);
        float4 u1 = *(const float4*)(LF + roff + 4);
        bf[0]=f2b(u0.x); bf[1]=f2b(u0.y); bf[2]=f2b(u0.z); bf[3]=f2b(u0.w);
        bf[4]=f2b(u1.x); bf[5]=f2b(u1.y); bf[6]=f2b(u1.z); bf[7]=f2b(u1.w);
      }
      acc[bi][rt] = __builtin_amdgcn_mfma_f32_16x16x32_bf16(a, bf, acc[bi][rt], 0, 0, 0);
    }
  }
  __syncthreads();

  // ---- t4 pack-write: t4[d][r*32+bb] = t3[bb*32+r]; 8 consecutive j per lane ----
  #pragma unroll
  for (int rt = 0; rt < 2; ++rt)
    #pragma unroll
    for (int rr = 0; rr < 4; ++rr) {
      short8 v;
      #pragma unroll
      for (int bi = 0; bi < 8; ++bi) v[bi] = f2b(acc[bi][rt][rr]);
      int r  = rt*16 + l15;
      int d  = l4*4 + rr;
      int j2 = r*32 + w*8;
      *(short8*)&xb[d*XP + swzj(j2)] = v;
    }
  __syncthreads();

  // ---- Stage 2: t5 = blockdiag(R) * t4 ----
  #pragma unroll
  for (int bi = 0; bi < 8; ++bi)
    #pragma unroll
    for (int rt = 0; rt < 2; ++rt) acc[bi][rt] = (f32x4){0.f,0.f,0.f,0.f};

  #pragma unroll
  for (int bi = 0; bi < 8; ++bi) {
    int bb = w*8 + bi;
    int j0 = bb*32 + l4*8;
    short8 a = *(const short8*)&xb[l15*XP + swzj(j0)];
    #pragma unroll
    for (int rt = 0; rt < 2; ++rt) {
      int roff = ((i*32 + bb)*32 + rt*16 + l15)*32 + l4*8;
      short8 bf;
      if (USEBF) {
        bf = *(const short8*)(RBs + roff);
      } else {
        float4 u0 = *(const float4*)(RF + roff);
        float4 u1 = *(const float4*)(RF + roff + 4);
        bf[0]=f2b(u0.x); bf[1]=f2b(u0.y); bf[2]=f2b(u0.z); bf[3]=f2b(u0.w);
        bf[4]=f2b(u1.x); bf[5]=f2b(u1.y); bf[6]=f2b(u1.z); bf[7]=f2b(u1.w);
      }
      acc[bi][rt] = __builtin_amdgcn_mfma_f32_16x16x32_bf16(a, bf, acc[bi][rt], 0, 0, 0);
    }
  }
  __syncthreads();

  // ---- Phase 5: scatter t5 -> xb2[jo][16 d] (b64, swizzled), scaled ----
  // t5 index m = bb2*32 + r2 lands at jo = ror10(m, kf)
  #pragma unroll
  for (int bi = 0; bi < 8; ++bi)
    #pragma unroll
    for (int rt = 0; rt < 2; ++rt) {
      int m  = (w*8 + bi)*32 + rt*16 + l15;
      int jo = ror10(m, kf);
      int sw = (jo >> 5) & 3;
      unsigned int lo = (unsigned short)f2b(acc[bi][rt][0] * scale)
                      | ((unsigned int)(unsigned short)f2b(acc[bi][rt][1] * scale) << 16);
      unsigned int hi = (unsigned short)f2b(acc[bi][rt][2] * scale)
                      | ((unsigned int)(unsigned short)f2b(acc[bi][rt][3] * scale) << 16);
      uint2 pv; pv.x = lo; pv.y = hi;
      *(uint2*)&xb[jo*16 + ((l4 ^ sw) << 2)] = pv;   // d-group l4 stored at (l4^sw)
    }
  __syncthreads();

  // ---- Phase 6: coalesced global write [s][kd] ----
  {
    short* Out = src ? Kh : Qh;
    size_t obase = ((size_t)bh * 1024) * 256 + i*64 + dc*16;
    #pragma unroll
    for (int it2 = 0; it2 < 4; ++it2) {
      int jo = it2*256 + tid;
      int sw = (jo >> 5) & 3;
      uint2 g[4];
      #pragma unroll
      for (int gg = 0; gg < 4; ++gg)
        g[gg] = *(const uint2*)&xb[jo*16 + (((gg ^ sw)) << 2)];
      int4v lo = {(int)g[0].x, (int)g[0].y, (int)g[1].x, (int)g[1].y};
      int4v hi = {(int)g[2].x, (int)g[2].y, (int)g[3].x, (int)g[3].y};
      short* op = Out + obase + (size_t)jo * 256;
      *(int4v*)(op)     = lo;
      *(int4v*)(op + 8) = hi;
    }
  }
}

// ------------------------------------------------------------------
// Kernel 2: batched GEMM  out[s,l] = sum_k Qhat[s,k]*Khat[l,k], K=256,
// 128x128 tiles. XCD-affine: xcd = bid&7 owns bh group xcd*4..+3
// (4MB panel working set = one XCD L2). Swapped-operand MFMA so the
// epilogue is float4 nontemporal stores (bypass L2, keep panels hot).
// ------------------------------------------------------------------
__global__ __launch_bounds__(256) void score_gemm(
    const short* __restrict__ Qh, const short* __restrict__ Kh,
    float* __restrict__ Out)
{
  const int bid  = blockIdx.x;
  const int xcd  = bid & 7;
  const int seq  = bid >> 3;
  const int bh   = (xcd << 2) | (seq & 3);
  const int tile = seq >> 2;               // 0..63
  const int tm   = (tile >> 3) << 7;
  const int tn   = (tile & 7) << 7;

  __shared__ short As[128*64];
  __shared__ short Bs[128*64];

  const int tid  = threadIdx.x;
  const int lane = tid & 63;
  const int w    = tid >> 6;
  const int wm   = (w >> 1) << 6;
  const int wn   = (w & 1) << 6;
  const int l15  = lane & 15;
  const int l4   = lane >> 4;

  const short* Qb = Qh + (size_t)bh * (1024*256);
  const short* Kb = Kh + (size_t)bh * (1024*256);

  const int lrow = lane >> 3;                    // row within 8-row segment
  const int kch  = (((lane & 7) ^ lrow) << 3);   // inverse-swizzled source k-offset

  f32x4 acc[4][4];
  #pragma unroll
  for (int fm = 0; fm < 4; ++fm)
    #pragma unroll
    for (int fn = 0; fn < 4; ++fn) acc[fm][fn] = (f32x4){0.f,0.f,0.f,0.f};

  for (int kt = 0; kt < 4; ++kt) {
    #pragma unroll
    for (int q0 = 0; q0 < 4; ++q0) {
      int seg = w*4 + q0;
      int row = seg*8 + lrow;
      const short* srcA = Qb + (size_t)(tm + row)*256 + kt*64 + kch;
      const short* srcB = Kb + (size_t)(tn + row)*256 + kt*64 + kch;
      __builtin_amdgcn_global_load_lds(
          (const __attribute__((address_space(1))) unsigned int*)srcA,
          (__attribute__((address_space(3))) unsigned int*)&As[seg*512], 16, 0, 0);
      __builtin_amdgcn_global_load_lds(
          (const __attribute__((address_space(1))) unsigned int*)srcB,
          (__attribute__((address_space(3))) unsigned int*)&Bs[seg*512], 16, 0, 0);
    }
    __syncthreads();

    #pragma unroll
    for (int kk = 0; kk < 2; ++kk) {
      short8 af[4], bf[4];
      #pragma unroll
      for (int fm = 0; fm < 4; ++fm) {
        int row = wm + fm*16 + l15;
        int kl  = kk*32 + l4*8;
        af[fm] = *(const short8*)&As[row*64 + (kl ^ ((row & 7) << 3))];
      }
      #pragma unroll
      for (int fn = 0; fn < 4; ++fn) {
        int row = wn + fn*16 + l15;
        int kl  = kk*32 + l4*8;
        bf[fn] = *(const short8*)&Bs[row*64 + (kl ^ ((row & 7) << 3))];
      }
      // swapped operands: D rows = K-side (l), D cols = Q-side (s)
      #pragma unroll
      for (int fm = 0; fm < 4; ++fm)
        #pragma unroll
        for (int fn = 0; fn < 4; ++fn)
          acc[fm][fn] = __builtin_amdgcn_mfma_f32_16x16x32_bf16(bf[fn], af[fm], acc[fm][fn], 0, 0, 0);
    }
    __syncthreads();
  }

  // Epilogue: lane holds 4 consecutive l at fixed s -> float4 nt stores.
  float* Ob = Out + ((size_t)bh << 20);
  #pragma unroll
  for (int fm = 0; fm < 4; ++fm) {
    int srow = tm + wm + fm*16 + l15;
    #pragma unroll
    for (int fn = 0; fn < 4; ++fn) {
      int lcol = tn + wn + fn*16 + l4*4;
      __builtin_nontemporal_store(acc[fm][fn],
          (f32x4*)(Ob + ((size_t)srow << 10) + lcol));
    }
  }
}

extern "C" void kernel_launch(void* const* d_in, const int* in_sizes, int n_in,
                              void* d_out, int out_size, void* d_ws, size_t ws_size,
                              hipStream_t stream) {
  const float* Q   = (const float*)d_in[0];
  const float* Kv  = (const float*)d_in[1];
  const float* M1L = (const float*)d_in[2];
  const float* M1R = (const float*)d_in[3];
  const float* M2L = (const float*)d_in[4];
  const float* M2R = (const float*)d_in[5];
  const float* W   = (const float*)d_in[6];
  const int* per   = (const int*)d_in[7];
  float* Out       = (float*)d_out;

  const size_t qsz = (size_t)32 * 1024 * 256;     // 8388608 shorts each
  short* Qhat = (short*)d_ws;
  short* Khat = Qhat + qsz;
  short* Lbf  = Khat + qsz;
  const size_t need = (qsz * 2 + (size_t)4 * 131072) * sizeof(short);
  const bool usebf = (ws_size >= need);

  if (usebf) {
    conv_lr<<<dim3(128), dim3(256), 0, stream>>>(M1L, M1R, M2L, M2R, Lbf);
    monarch_transform2<true><<<dim3(1024), dim3(256), 0, stream>>>(
        Q, Kv, M1L, M1R, M2L, M2R, Lbf, W, per, Qhat, Khat);
  } else {
    monarch_transform2<false><<<dim3(1024), dim3(256), 0, stream>>>(
        Q, Kv, M1L, M1R, M2L, M2R, Lbf, W, per, Qhat, Khat);
  }

  score_gemm<<<dim3(2048), dim3(256), 0, stream>>>(Qhat, Khat, Out);
}